// Round 7
// baseline (307.684 us; speedup 1.0000x reference)
//
#include <hip/hip_runtime.h>
#include <hip/hip_bf16.h>

typedef unsigned short ushort_t;
typedef __attribute__((ext_vector_type(8))) short short8;
typedef __attribute__((ext_vector_type(4))) float f32x4;

#define M_DIM 8192
#define N_DIM 8192
#define K_DIM 2048
#define BM 256
#define BN 256
#define BK 64
#define NT (K_DIM / BK)    // 32 K-tiles per output tile
#define TT 4               // output tiles per block (2x2 supertile)
#define GTOT (TT * NT)     // 128 loop iterations

__device__ __forceinline__ ushort_t f2bf(float f) {
    union { float f; unsigned u; } v; v.f = f;
    unsigned r = v.u + 0x7fffu + ((v.u >> 16) & 1u);   // RNE
    return (ushort_t)(r >> 16);
}

__device__ __forceinline__ void async_copy16(const void* g, void* l) {
    __builtin_amdgcn_global_load_lds(
        (const __attribute__((address_space(1))) void*)g,
        (__attribute__((address_space(3))) void*)l, 16, 0, 0);
}

#define BAR() __builtin_amdgcn_s_barrier()
#define LGKM0() do { asm volatile("s_waitcnt lgkmcnt(0)" ::: "memory"); \
                     __builtin_amdgcn_sched_barrier(0); } while (0)

// ---- kernel 1: x (f32) -> A (bf16) ----
__global__ __launch_bounds__(256) void convert_x(const float* __restrict__ x,
                                                 ushort_t* __restrict__ A) {
    int t = blockIdx.x * 256 + threadIdx.x;
    const float4* p = (const float4*)x + (size_t)t * 2;
    float4 a = p[0], b = p[1];
    short8 o;
    o[0] = (short)f2bf(a.x); o[1] = (short)f2bf(a.y);
    o[2] = (short)f2bf(a.z); o[3] = (short)f2bf(a.w);
    o[4] = (short)f2bf(b.x); o[5] = (short)f2bf(b.y);
    o[6] = (short)f2bf(b.z); o[7] = (short)f2bf(b.w);
    *(short8*)(A + (size_t)t * 8) = o;
}

// ---- kernel 2: codebook gather -> Bt (bf16, N x K layout) ----
__global__ __launch_bounds__(256) void dequant_wt(const int* __restrict__ indices,
                                                  const float* __restrict__ codebook,
                                                  ushort_t* __restrict__ Bt) {
    int g = blockIdx.x;                       // column group 0..1023
    int i = blockIdx.y * 256 + threadIdx.x;   // K row 0..2047
    int idx = indices[(size_t)i * 1024 + g];
    const float4* cb = (const float4*)(codebook + (size_t)idx * 8);
    float4 lo = cb[0], hi = cb[1];
    size_t base = (size_t)g * 8 * K_DIM + i;
    Bt[base + 0 * K_DIM] = f2bf(lo.x);
    Bt[base + 1 * K_DIM] = f2bf(lo.y);
    Bt[base + 2 * K_DIM] = f2bf(lo.z);
    Bt[base + 3 * K_DIM] = f2bf(lo.w);
    Bt[base + 4 * K_DIM] = f2bf(hi.x);
    Bt[base + 5 * K_DIM] = f2bf(hi.y);
    Bt[base + 6 * K_DIM] = f2bf(hi.z);
    Bt[base + 7 * K_DIM] = f2bf(hi.w);
}

// ---- 8-phase 256x256 GEMM helpers ----
__device__ __forceinline__ void load_af4(const ushort_t* p, const int (&off)[4][2],
                                         short8 (&fr)[4][2]) {
#pragma unroll
    for (int i = 0; i < 4; ++i)
#pragma unroll
        for (int kk = 0; kk < 2; ++kk)
            fr[i][kk] = *(const short8*)((const char*)p + off[i][kk]);
}

__device__ __forceinline__ void load_bf2(const ushort_t* p, const int (&off)[2][2],
                                         short8 (&fr)[2][2]) {
#pragma unroll
    for (int j = 0; j < 2; ++j)
#pragma unroll
        for (int kk = 0; kk < 2; ++kk)
            fr[j][kk] = *(const short8*)((const char*)p + off[j][kk]);
}

__device__ __forceinline__ void mfma16(const short8 (&af)[4][2], const short8 (&bf)[2][2],
                                       f32x4 (&acc)[8][4], int I0, int J0) {
    __builtin_amdgcn_s_setprio(1);
#pragma unroll
    for (int kk = 0; kk < 2; ++kk)
#pragma unroll
        for (int i = 0; i < 4; ++i)
#pragma unroll
            for (int j = 0; j < 2; ++j)
                acc[I0 + i][J0 + j] = __builtin_amdgcn_mfma_f32_16x16x32_bf16(
                    af[i][kk], bf[j][kk], acc[I0 + i][J0 + j], 0, 0, 0);
    __builtin_amdgcn_s_setprio(0);
}

// tile-walk within 2x2 supertile: t=0..3 -> (tm,tn) = (0,0),(0,1),(1,1),(1,0)
__device__ __forceinline__ int tile_tm(int t) { return t >> 1; }
__device__ __forceinline__ int tile_tn(int t) { return (t & 1) ^ (t >> 1); }

// ---- kernel 3: persistent 4-tile 256^2 8-phase GEMM + bias ----
__global__ __launch_bounds__(512, 2) void gemm_256_8phase(const ushort_t* __restrict__ A,
                                                          const ushort_t* __restrict__ Bt,
                                                          const float* __restrict__ bias,
                                                          float* __restrict__ C) {
    __shared__ __align__(16) ushort_t lds_a[2][2][128 * 64];
    __shared__ __align__(16) ushort_t lds_b[2][2][128 * 64];

    // 2D XCD-rectangle swizzle at supertile (512x512) level; 16x16 supertiles.
    const int bid = blockIdx.x;                  // 0..255
    const int x = bid & 7;                       // XCD
    const int u = bid >> 3;                      // 0..31
    const int st_m = (x >> 1) * 4 + (u & 3);     // 0..15
    const int st_n = (x & 1) * 8 + ((u >> 2) & 7);
    const int m_base = st_m * 512;
    const int n_base = st_n * 512;

    const int tid = threadIdx.x;
    const int lane = tid & 63;
    const int wid = tid >> 6;              // 0..7
    const int wm = wid >> 2, wn = wid & 3; // 2 x 4 wave grid
    const int lane15 = lane & 15, laneq = lane >> 4;

    // --- staging addresses (supertile base; per-tile offset added in STAGE) ---
    const int G0 = tid, G1 = 512 + tid;
    const int r0 = G0 >> 3, r1 = G1 >> 3;                 // half-tile row 0..127
    const int c0 = (G0 & 7) ^ (r0 & 7), c1 = (G1 & 7) ^ (r1 & 7);
    const size_t aoff0 = (size_t)(m_base + r0) * K_DIM + c0 * 8;
    const size_t aoff1 = (size_t)(m_base + r1) * K_DIM + c1 * 8;
    const size_t boff0 = (size_t)(n_base + r0) * K_DIM + c0 * 8;
    const size_t boff1 = (size_t)(n_base + r1) * K_DIM + c1 * 8;
    const int dq0 = G0 * 16, dq1 = G1 * 16;
    const size_t HOFF = (size_t)128 * K_DIM;              // half 1 row offset

    // h = global K-tile index 0..GTOT-1; tile = h>>5, within-tile k = h&31, slot = h&1
#define STAGE_A(h, hh) do { \
        int _t = (h) >> 5, _k = (h) & 31; \
        size_t _mo = (size_t)(tile_tm(_t) * 256) * K_DIM; \
        char* _d = (char*)&lds_a[(h) & 1][hh][0]; \
        async_copy16(A + aoff0 + _mo + (size_t)(hh) * HOFF + (size_t)_k * BK, _d + dq0); \
        async_copy16(A + aoff1 + _mo + (size_t)(hh) * HOFF + (size_t)_k * BK, _d + dq1); \
    } while (0)
#define STAGE_B(h, hh) do { \
        int _t = (h) >> 5, _k = (h) & 31; \
        size_t _no = (size_t)(tile_tn(_t) * 256) * K_DIM; \
        char* _d = (char*)&lds_b[(h) & 1][hh][0]; \
        async_copy16(Bt + boff0 + _no + (size_t)(hh) * HOFF + (size_t)_k * BK, _d + dq0); \
        async_copy16(Bt + boff1 + _no + (size_t)(hh) * HOFF + (size_t)_k * BK, _d + dq1); \
    } while (0)

    // --- swizzled ds_read byte offsets (within a [128][64] half) ---
    int offA[4][2], offB[2][2];
#pragma unroll
    for (int i = 0; i < 4; ++i) {
        int row = wm * 64 + i * 16 + lane15;
#pragma unroll
        for (int kk = 0; kk < 2; ++kk)
            offA[i][kk] = row * 128 + (((kk * 4 + laneq) ^ (row & 7)) * 16);
    }
#pragma unroll
    for (int j = 0; j < 2; ++j) {
        int row = wn * 32 + j * 16 + lane15;
#pragma unroll
        for (int kk = 0; kk < 2; ++kk)
            offB[j][kk] = row * 128 + (((kk * 4 + laneq) ^ (row & 7)) * 16);
    }

    f32x4 acc[8][4];
#pragma unroll
    for (int i = 0; i < 8; ++i)
#pragma unroll
        for (int j = 0; j < 4; ++j) acc[i][j] = (f32x4){0.f, 0.f, 0.f, 0.f};

    // --- prologue: K-tile 0 fully + {Bh0,Bh1,Ah1} of K-tile 1 ---
    STAGE_A(0, 0); STAGE_B(0, 0); STAGE_B(0, 1); STAGE_A(0, 1);
    STAGE_B(1, 0); STAGE_B(1, 1); STAGE_A(1, 1);
    asm volatile("s_waitcnt vmcnt(6)" ::: "memory");
    BAR();

    short8 af[4][2], bf0[2][2], bf1[2][2];

    for (int g = 0; g < GTOT; ++g) {
        const int d = g & 1;
        // P1: (m0,n0) — reads A0(8) + B0(4); stage Ah0(g+1)
        load_af4(&lds_a[d][0][0], offA, af);
        load_bf2(&lds_b[d][0][0], offB, bf0);
        if (g + 1 < GTOT) STAGE_A(g + 1, 0);
        asm volatile("s_waitcnt lgkmcnt(8)" ::: "memory");
        BAR(); LGKM0();
        mfma16(af, bf0, acc, 0, 0);
        BAR();
        // P2: (m0,n1) — reads B1(4); stage Bh0(g+2)
        load_bf2(&lds_b[d][1][0], offB, bf1);
        if (g + 2 < GTOT) STAGE_B(g + 2, 0);
        BAR(); LGKM0();
        mfma16(af, bf1, acc, 0, 2);
        BAR();
        // P3: (m1,n1) — reads A1(8); stage Bh1(g+2)
        load_af4(&lds_a[d][1][0], offA, af);
        if (g + 2 < GTOT) STAGE_B(g + 2, 1);
        BAR(); LGKM0();
        mfma16(af, bf1, acc, 4, 2);
        BAR();
        // P4: (m1,n0) — zero reads; stage Ah1(g+2); counted vmcnt
        if (g + 2 < GTOT) STAGE_A(g + 2, 1);
        BAR(); LGKM0();
        mfma16(af, bf0, acc, 4, 0);
        if (g < GTOT - 2) { asm volatile("s_waitcnt vmcnt(6)" ::: "memory"); }
        else              { asm volatile("s_waitcnt vmcnt(0)" ::: "memory"); }
        BAR();

        // --- tile boundary: store finished tile, re-zero acc ---
        if ((g & 31) == 31) {
            const int t = g >> 5;
            const int tm0 = m_base + tile_tm(t) * 256;
            const int tn0 = n_base + tile_tn(t) * 256;
#pragma unroll
            for (int ig = 0; ig < 8; ++ig) {
                int row = tm0 + (ig >> 2) * 128 + wm * 64 + (ig & 3) * 16 + laneq * 4;
#pragma unroll
                for (int jg = 0; jg < 4; ++jg) {
                    int col = tn0 + (jg >> 1) * 128 + wn * 32 + (jg & 1) * 16 + lane15;
                    float bv = bias[col];
                    f32x4 v = acc[ig][jg];
#pragma unroll
                    for (int q2 = 0; q2 < 4; ++q2)
                        C[(size_t)(row + q2) * N_DIM + col] = v[q2] + bv;
                }
            }
#pragma unroll
            for (int i = 0; i < 8; ++i)
#pragma unroll
                for (int j = 0; j < 4; ++j) acc[i][j] = (f32x4){0.f, 0.f, 0.f, 0.f};
        }
    }
#undef STAGE_A
#undef STAGE_B
}

extern "C" void kernel_launch(void* const* d_in, const int* in_sizes, int n_in,
                              void* d_out, int out_size, void* d_ws, size_t ws_size,
                              hipStream_t stream) {
    const float* x = (const float*)d_in[0];
    const float* codebook = (const float*)d_in[1];
    const int* indices = (const int*)d_in[2];      // harness: integer -> int32
    const float* bias = (const float*)d_in[3];
    float* out = (float*)d_out;

    ushort_t* A  = (ushort_t*)d_ws;                               // 32 MB
    ushort_t* Bt = (ushort_t*)d_ws + (size_t)M_DIM * K_DIM;       // 32 MB

    convert_x<<<dim3(M_DIM * K_DIM / (256 * 8)), 256, 0, stream>>>(x, A);
    dequant_wt<<<dim3(1024, 8), 256, 0, stream>>>(indices, codebook, Bt);
    gemm_256_8phase<<<dim3(256), 512, 0, stream>>>(A, Bt, bias, out);
}

// Round 8
// 286.287 us; speedup vs baseline: 1.0747x; 1.0747x over previous
//
#include <hip/hip_runtime.h>
#include <hip/hip_bf16.h>

typedef unsigned short ushort_t;
typedef __attribute__((ext_vector_type(8))) short short8;
typedef __attribute__((ext_vector_type(4))) float f32x4;

#define M_DIM 8192
#define N_DIM 8192
#define K_DIM 2048
#define BM 256
#define BN 256
#define BK 64
#define NT (K_DIM / BK)   // 32 K-tiles

__device__ __forceinline__ ushort_t f2bf(float f) {
    union { float f; unsigned u; } v; v.f = f;
    unsigned r = v.u + 0x7fffu + ((v.u >> 16) & 1u);   // RNE
    return (ushort_t)(r >> 16);
}

__device__ __forceinline__ void async_copy16(const void* g, void* l) {
    __builtin_amdgcn_global_load_lds(
        (const __attribute__((address_space(1))) void*)g,
        (__attribute__((address_space(3))) void*)l, 16, 0, 0);
}

#define BAR() __builtin_amdgcn_s_barrier()
#define LGKM0() do { asm volatile("s_waitcnt lgkmcnt(0)" ::: "memory"); \
                     __builtin_amdgcn_sched_barrier(0); } while (0)

// ---- kernel 1: x (f32) -> A (bf16) ----
__global__ __launch_bounds__(256) void convert_x(const float* __restrict__ x,
                                                 ushort_t* __restrict__ A) {
    int t = blockIdx.x * 256 + threadIdx.x;
    const float4* p = (const float4*)x + (size_t)t * 2;
    float4 a = p[0], b = p[1];
    short8 o;
    o[0] = (short)f2bf(a.x); o[1] = (short)f2bf(a.y);
    o[2] = (short)f2bf(a.z); o[3] = (short)f2bf(a.w);
    o[4] = (short)f2bf(b.x); o[5] = (short)f2bf(b.y);
    o[6] = (short)f2bf(b.z); o[7] = (short)f2bf(b.w);
    *(short8*)(A + (size_t)t * 8) = o;
}

// ---- kernel 2: codebook gather -> Bt (bf16, N x K layout) ----
__global__ __launch_bounds__(256) void dequant_wt(const int* __restrict__ indices,
                                                  const float* __restrict__ codebook,
                                                  ushort_t* __restrict__ Bt) {
    int g = blockIdx.x;                       // column group 0..1023
    int i = blockIdx.y * 256 + threadIdx.x;   // K row 0..2047
    int idx = indices[(size_t)i * 1024 + g];
    const float4* cb = (const float4*)(codebook + (size_t)idx * 8);
    float4 lo = cb[0], hi = cb[1];
    size_t base = (size_t)g * 8 * K_DIM + i;
    Bt[base + 0 * K_DIM] = f2bf(lo.x);
    Bt[base + 1 * K_DIM] = f2bf(lo.y);
    Bt[base + 2 * K_DIM] = f2bf(lo.z);
    Bt[base + 3 * K_DIM] = f2bf(lo.w);
    Bt[base + 4 * K_DIM] = f2bf(hi.x);
    Bt[base + 5 * K_DIM] = f2bf(hi.y);
    Bt[base + 6 * K_DIM] = f2bf(hi.z);
    Bt[base + 7 * K_DIM] = f2bf(hi.w);
}

// ---- helpers ----
__device__ __forceinline__ void load_af4(const ushort_t* p, const int (&off)[4][2],
                                         short8 (&fr)[4][2]) {
#pragma unroll
    for (int i = 0; i < 4; ++i)
#pragma unroll
        for (int kk = 0; kk < 2; ++kk)
            fr[i][kk] = *(const short8*)((const char*)p + off[i][kk]);
}

__device__ __forceinline__ void load_bf2(const ushort_t* p, const int (&off)[2][2],
                                         short8 (&fr)[2][2]) {
#pragma unroll
    for (int j = 0; j < 2; ++j)
#pragma unroll
        for (int kk = 0; kk < 2; ++kk)
            fr[j][kk] = *(const short8*)((const char*)p + off[j][kk]);
}

__device__ __forceinline__ void mfma16(const short8 (&af)[4][2], const short8 (&bf)[2][2],
                                       f32x4 (&acc)[8][4], int I0, int J0) {
    __builtin_amdgcn_s_setprio(1);
#pragma unroll
    for (int kk = 0; kk < 2; ++kk)
#pragma unroll
        for (int i = 0; i < 4; ++i)
#pragma unroll
            for (int j = 0; j < 2; ++j)
                acc[I0 + i][J0 + j] = __builtin_amdgcn_mfma_f32_16x16x32_bf16(
                    af[i][kk], bf[j][kk], acc[I0 + i][J0 + j], 0, 0, 0);
    __builtin_amdgcn_s_setprio(0);
}

// ---- kernel 3: C = A(MxK) * Bt(NxK)^T + bias ; 256^2 tile ----
// R8: 4 barriers/K-tile (1 per phase). Stage placement re-derived so every
// stage target's last reader drained >=1 barrier before the stage issues:
//   P1: stage Ah0(g+1)+Ah1(g+1)   (slots read at P1/P3 of g-1)
//   P3: stage Bh0(g+2)            (slot read at P1 of g, 2 barriers back)
//   P4: stage Bh1(g+2)            (slot read at P2 of g, 1 barrier back)
// vmcnt(4) at P4 retires exactly tile g+1's 8 loads. No post-MFMA barriers ->
// next-phase ds_reads overlap other waves' MFMA.
__global__ __launch_bounds__(512, 2) void gemm_256_8phase(const ushort_t* __restrict__ A,
                                                          const ushort_t* __restrict__ Bt,
                                                          const float* __restrict__ bias,
                                                          float* __restrict__ C) {
    __shared__ __align__(16) ushort_t lds_a[2][2][128 * 64];
    __shared__ __align__(16) ushort_t lds_b[2][2][128 * 64];

    // 2D XCD-rectangle swizzle (R5: FETCH 542->197 MB)
    const int bid = blockIdx.x;                  // 0..1023
    const int x = bid & 7;                       // XCD
    const int q = bid >> 3;                      // 0..127
    const int mt = ((x >> 1) << 2) + (q & 3) + (((q >> 5) & 1) << 4);
    const int nt = ((x & 1) << 3) + ((q >> 2) & 7) + (((q >> 6) & 1) << 4);
    const int m0 = mt * BM;
    const int n0 = nt * BN;

    const int tid = threadIdx.x;
    const int lane = tid & 63;
    const int wid = tid >> 6;              // 0..7
    const int wm = wid >> 2, wn = wid & 3; // 2 x 4 wave grid
    const int lane15 = lane & 15, laneq = lane >> 4;

    // --- staging addresses: linear LDS dest granule -> inverse-swizzled global col ---
    const int G0 = tid, G1 = 512 + tid;
    const int r0 = G0 >> 3, r1 = G1 >> 3;                 // half-tile row 0..127
    const int c0 = (G0 & 7) ^ (r0 & 7), c1 = (G1 & 7) ^ (r1 & 7);
    const size_t aoff0 = (size_t)(m0 + r0) * K_DIM + c0 * 8;
    const size_t aoff1 = (size_t)(m0 + r1) * K_DIM + c1 * 8;
    const size_t boff0 = (size_t)(n0 + r0) * K_DIM + c0 * 8;
    const size_t boff1 = (size_t)(n0 + r1) * K_DIM + c1 * 8;
    const int dq0 = G0 * 16, dq1 = G1 * 16;
    const size_t HOFF = (size_t)128 * K_DIM;              // half-1 row offset

#define STAGE_A(gt, hh) do { \
        char* _d = (char*)&lds_a[(gt) & 1][hh][0]; \
        async_copy16(A + aoff0 + (size_t)(hh) * HOFF + (size_t)(gt) * BK, _d + dq0); \
        async_copy16(A + aoff1 + (size_t)(hh) * HOFF + (size_t)(gt) * BK, _d + dq1); \
    } while (0)
#define STAGE_B(gt, hh) do { \
        char* _d = (char*)&lds_b[(gt) & 1][hh][0]; \
        async_copy16(Bt + boff0 + (size_t)(hh) * HOFF + (size_t)(gt) * BK, _d + dq0); \
        async_copy16(Bt + boff1 + (size_t)(hh) * HOFF + (size_t)(gt) * BK, _d + dq1); \
    } while (0)

    // --- swizzled ds_read byte offsets (within a [128][64] half) ---
    int offA[4][2], offB[2][2];
#pragma unroll
    for (int i = 0; i < 4; ++i) {
        int row = wm * 64 + i * 16 + lane15;
#pragma unroll
        for (int kk = 0; kk < 2; ++kk)
            offA[i][kk] = row * 128 + (((kk * 4 + laneq) ^ (row & 7)) * 16);
    }
#pragma unroll
    for (int j = 0; j < 2; ++j) {
        int row = wn * 32 + j * 16 + lane15;
#pragma unroll
        for (int kk = 0; kk < 2; ++kk)
            offB[j][kk] = row * 128 + (((kk * 4 + laneq) ^ (row & 7)) * 16);
    }

    f32x4 acc[8][4];
#pragma unroll
    for (int i = 0; i < 8; ++i)
#pragma unroll
        for (int j = 0; j < 4; ++j) acc[i][j] = (f32x4){0.f, 0.f, 0.f, 0.f};

    // --- prologue: tile0 (A0,A1,B0,B1) + {Bh0,Bh1} of tile1 = 12 loads ---
    STAGE_A(0, 0); STAGE_A(0, 1); STAGE_B(0, 0); STAGE_B(0, 1);
    STAGE_B(1, 0); STAGE_B(1, 1);
    asm volatile("s_waitcnt vmcnt(4)" ::: "memory");   // tile0 landed; B(1) in flight
    BAR();

    short8 af[4][2], bf0[2][2], bf1[2][2];

    for (int g = 0; g < NT; ++g) {
        const int d = g & 1;
        // P1: (m0,n0) — reads A0(8)+B0(4); stage Ah0(g+1)+Ah1(g+1)
        load_af4(&lds_a[d][0][0], offA, af);
        load_bf2(&lds_b[d][0][0], offB, bf0);
        if (g + 1 < NT) { STAGE_A(g + 1, 0); STAGE_A(g + 1, 1); }
        BAR(); LGKM0();
        mfma16(af, bf0, acc, 0, 0);
        // P2: (m0,n1) — reads B1(4); af held; no stage
        load_bf2(&lds_b[d][1][0], offB, bf1);
        BAR(); LGKM0();
        mfma16(af, bf1, acc, 0, 2);
        // P3: (m1,n1) — reads A1(8); bf1 held; stage Bh0(g+2)
        load_af4(&lds_a[d][1][0], offA, af);
        if (g + 2 < NT) STAGE_B(g + 2, 0);
        BAR(); LGKM0();
        mfma16(af, bf1, acc, 4, 2);
        // P4: (m1,n0) — zero reads; af(A1)+bf0 held; stage Bh1(g+2); counted vmcnt
        if (g + 2 < NT) STAGE_B(g + 2, 1);
        if (g < NT - 2) { asm volatile("s_waitcnt vmcnt(4)" ::: "memory"); }
        else            { asm volatile("s_waitcnt vmcnt(0)" ::: "memory"); }
        __builtin_amdgcn_sched_barrier(0);
        BAR();
        mfma16(af, bf0, acc, 4, 0);
    }

    // --- epilogue: bias + f32 store ---
#pragma unroll
    for (int ig = 0; ig < 8; ++ig) {
        int row = m0 + (ig >> 2) * 128 + wm * 64 + (ig & 3) * 16 + laneq * 4;
#pragma unroll
        for (int jg = 0; jg < 4; ++jg) {
            int col = n0 + (jg >> 1) * 128 + wn * 32 + (jg & 1) * 16 + lane15;
            float bv = bias[col];
            f32x4 v = acc[ig][jg];
#pragma unroll
            for (int q2 = 0; q2 < 4; ++q2)
                C[(size_t)(row + q2) * N_DIM + col] = v[q2] + bv;
        }
    }
#undef STAGE_A
#undef STAGE_B
}

extern "C" void kernel_launch(void* const* d_in, const int* in_sizes, int n_in,
                              void* d_out, int out_size, void* d_ws, size_t ws_size,
                              hipStream_t stream) {
    const float* x = (const float*)d_in[0];
    const float* codebook = (const float*)d_in[1];
    const int* indices = (const int*)d_in[2];      // harness: integer -> int32
    const float* bias = (const float*)d_in[3];
    float* out = (float*)d_out;

    ushort_t* A  = (ushort_t*)d_ws;                               // 32 MB
    ushort_t* Bt = (ushort_t*)d_ws + (size_t)M_DIM * K_DIM;       // 32 MB

    convert_x<<<dim3(M_DIM * K_DIM / (256 * 8)), 256, 0, stream>>>(x, A);
    dequant_wt<<<dim3(1024, 8), 256, 0, stream>>>(indices, codebook, Bt);
    gemm_256_8phase<<<dim3((M_DIM / BM) * (N_DIM / BN)), 512, 0, stream>>>(A, Bt, bias, out);
}